// Round 9
// baseline (1230.582 us; speedup 1.0000x reference)
//
#include <hip/hip_runtime.h>
#include <math.h>
#include <stdint.h>

// Problem constants (FPModule: knn-interpolate + 2-layer MLP)
#define Bn    4
#define Nn    2048
#define Mn    8192
#define CIN   256
#define CSKIP 128
#define HID   256
#define COUT  128
#define KTOT  384   // CIN + CSKIP

// spatial grid: h=0.25 over [-4,4] (points are ~N(0,1); density ~130/unit^3
// centrally -> ~2 pts per cell, ~55 per 27-cell box)
#define GC    32                // cells per axis
#define NCC   32768             // GC^3
#define GLO   -4.0f
#define GH    0.25f

typedef short bf16x8 __attribute__((ext_vector_type(8)));
typedef float f32x16 __attribute__((ext_vector_type(16)));

__device__ __forceinline__ ushort f2bf(float f) {
    union { float f; unsigned u; } v; v.f = f;
    return (ushort)((v.u + 0x7fffu + ((v.u >> 16) & 1u)) >> 16);   // RNE
}

// 5-op sorted-insert of key k into (kA <= kB <= kC), keeping 3 smallest.
// Order-independent: final triple = 3 smallest keys of the inserted multiset.
#define INSERT3(kA, kB, kC, k)            \
    do {                                  \
        const double _t = fmax(kA, k);    \
        kA = fmin(kA, k);                 \
        const double _u = fmax(kB, _t);   \
        kB = fmin(kB, _t);                \
        kC = fmin(kC, _u);                \
    } while (0)

__device__ __forceinline__ int cellof(float v) {
    int c = (int)floorf((v - GLO) / GH);
    return min(max(c, 0), GC - 1);
}

// ---------------------------------------------------------------------------
// Kernel A: per-batch grid build (one 512-thread block per batch).
// Global hist/cnt (32K cells won't fit LDS): zero -> histogram -> chunked
// prefix (LDS partials, serial 512-scan by t0) -> re-zero cnt -> scatter.
// spos4 = (2px,2py,2pz,pp): pp via explicit _rn ops; 2x exact, so the query
// side dot2 is bit-identical to 2*dot of the reference. sidx keeps ORIGINAL
// point index (tie-break + feature gather).
// ---------------------------------------------------------------------------
__global__ __launch_bounds__(512) void build_grid(
    const float* __restrict__ pos,       // (B*N, 3)
    float4* __restrict__ spos4,          // (B*N) cell-sorted
    int*    __restrict__ sidx,           // (B*N) original index
    int*    __restrict__ cellStart,      // (B, NCC+1)
    int*    __restrict__ cnt)            // (B, NCC) scratch
{
    __shared__ int part[512];

    const int b = blockIdx.x, tid = threadIdx.x;
    int* cs = cellStart + (size_t)b * (NCC + 1);
    int* cn = cnt + (size_t)b * NCC;

    for (int c = tid; c < NCC; c += 512) cn[c] = 0;
    __syncthreads();

    int cellv[4];
#pragma unroll
    for (int t = 0; t < 4; ++t) {
        const int i = tid * 4 + t;                 // 0..2047
        const float* p = pos + ((size_t)b * Nn + i) * 3;
        const int cell = (cellof(p[2]) * GC + cellof(p[1])) * GC + cellof(p[0]);
        cellv[t] = cell;
        atomicAdd(&cn[cell], 1);
    }
    __syncthreads();

    // prefix over 32768 cells: 64/thread
    const int base = tid * 64;
    int s = 0;
    for (int j = 0; j < 64; ++j) s += cn[base + j];
    part[tid] = s;
    __syncthreads();
    if (tid == 0) {
        int acc = 0;
        for (int t = 0; t < 512; ++t) { const int v = part[t]; part[t] = acc; acc += v; }
    }
    __syncthreads();
    int acc = part[tid];
    for (int j = 0; j < 64; ++j) { const int v = cn[base + j]; cs[base + j] = acc; acc += v; }
    if (tid == 511) cs[NCC] = acc;                 // == Nn
    __syncthreads();

    for (int c = tid; c < NCC; c += 512) cn[c] = 0;   // re-zero for scatter
    __syncthreads();

#pragma unroll
    for (int t = 0; t < 4; ++t) {
        const int i = tid * 4 + t;
        const float* p = pos + ((size_t)b * Nn + i) * 3;
        const float p0 = p[0], p1 = p[1], p2 = p[2];
        const float pp = __fadd_rn(__fadd_rn(__fmul_rn(p0, p0), __fmul_rn(p1, p1)),
                                   __fmul_rn(p2, p2));
        const int slot = cs[cellv[t]] + atomicAdd(&cn[cellv[t]], 1);
        spos4[(size_t)b * Nn + slot] = make_float4(2.0f * p0, 2.0f * p1, 2.0f * p2, pp);
        sidx [(size_t)b * Nn + slot] = i;
    }
}

// ---------------------------------------------------------------------------
// Kernel B (fused mid): block roles by blockIdx.x:
//   [0,1024)       KNN: 32 queries/block, 8 threads/query. Shell-expanding
//                  scan: pass covers cheb in (prevk, k]; cells distributed
//                  round-robin over the 8 lanes; per-lane partial top-3 f64
//                  keys; butterfly shfl_xor merge (disjoint lane summaries)
//                  gives every lane the merged triple for a uniform stop
//                  decision (R8-validated slab bound, margin 1e-4 >> 2e-6
//                  f32 rounding gap). key = double(d)|orig_idx == lex (d,idx)
//                  == top_k value-then-lowest-index order.
//   [1024,5120)    Abig[:,256:384] = bf16(x_skip)
//   [5120,5216)    W1T[n][k] = bf16(W1[k][n])
//   [5216,5248)    W2T[n][k] = bf16(W2[k][n])
//   [5248,5760)    tail: copy pos_skip + synthesize batch_skip into d_out
// ---------------------------------------------------------------------------
__global__ __launch_bounds__(256) void knn_gather(
    const float* __restrict__ x,          // (B*N, CIN)
    const float4* __restrict__ spos4,     // cell-sorted packed points
    const int*    __restrict__ sidx,      // original indices
    const int*    __restrict__ cellStart, // (B, NCC+1)
    const float* __restrict__ xs,         // (B*M, CSKIP)
    const float* __restrict__ pos_skip,   // (B*M, 3)
    const float* __restrict__ W1, const float* __restrict__ W2,
    ushort* __restrict__ Abig,            // (B*M, KTOT) bf16
    ushort* __restrict__ W1T, ushort* __restrict__ W2T,
    float* __restrict__ tail_dst)         // d_out + B*M*COUT
{
    __shared__ int   rIdx[32][3];
    __shared__ float rW[32][3];           // premultiplied w_i/den

    const int bid = blockIdx.x;
    const int tid = threadIdx.x;

    if (bid >= 1024) {
        // ---------------- aux roles ----------------
        const int cb = bid - 1024;
        if (cb < 4096) {
            const int q   = cb * 256 + tid;        // quad over 32768x128
            const int row = q >> 5;
            const int cq  = (q & 31) * 4;
            const float4 v = *(const float4*)(xs + (size_t)row * CSKIP + cq);
            ushort4 o; o.x = f2bf(v.x); o.y = f2bf(v.y); o.z = f2bf(v.z); o.w = f2bf(v.w);
            *(ushort4*)(Abig + (size_t)row * KTOT + CIN + cq) = o;
        } else if (cb < 4192) {
            const int q  = (cb - 4096) * 256 + tid;   // 24576 quads: n*96 + kq
            const int n  = q / 96;
            const int kq = (q % 96) * 4;
            ushort4 o;
            o.x = f2bf(W1[(size_t)(kq + 0) * HID + n]);
            o.y = f2bf(W1[(size_t)(kq + 1) * HID + n]);
            o.z = f2bf(W1[(size_t)(kq + 2) * HID + n]);
            o.w = f2bf(W1[(size_t)(kq + 3) * HID + n]);
            *(ushort4*)(W1T + (size_t)n * KTOT + kq) = o;
        } else if (cb < 4224) {
            const int q  = (cb - 4192) * 256 + tid;   // 8192 quads: n*64 + kq
            const int n  = q >> 6;
            const int kq = (q & 63) * 4;
            ushort4 o;
            o.x = f2bf(W2[(size_t)(kq + 0) * COUT + n]);
            o.y = f2bf(W2[(size_t)(kq + 1) * COUT + n]);
            o.z = f2bf(W2[(size_t)(kq + 2) * COUT + n]);
            o.w = f2bf(W2[(size_t)(kq + 3) * COUT + n]);
            *(ushort4*)(W2T + (size_t)n * HID + kq) = o;
        } else {
            const int i = (cb - 4224) * 256 + tid;
            const int nPos = Bn * Mn * 3;             // 98304
            if (i < nPos) tail_dst[i] = pos_skip[i];
            else          tail_dst[i] = (float)((i - nPos) >> 13);
        }
        return;
    }

    // ---------------- KNN role ----------------
    const int g      = tid >> 3;           // query group 0..31
    const int t8     = tid & 7;            // lane within group
    const int blockQ = bid * 32;
    const int b      = blockQ / Mn;        // 256 blocks per batch

    const int q = blockQ + g;
    const float* qp = pos_skip + (size_t)q * 3;
    const float q0 = qp[0], q1 = qp[1], q2 = qp[2];
    const float qq = __fadd_rn(__fadd_rn(__fmul_rn(q0, q0), __fmul_rn(q1, q1)),
                               __fmul_rn(q2, q2));
    const int cx = cellof(q0), cy = cellof(q1), cz = cellof(q2);

    const int*    __restrict__ cs = cellStart + (size_t)b * (NCC + 1);
    const float4* __restrict__ cp = spos4 + (size_t)b * Nn;
    const int*    __restrict__ ci = sidx  + (size_t)b * Nn;

    double kA = (double)INFINITY, kB = (double)INFINITY, kC = (double)INFINITY;
    double mA, mB, mC;

    int prevk = -1;
    int k = 1;                              // first pass: cheb 0..1 (27 cells)
    for (;;) {
        const int zlo = max(cz - k, 0), zhi = min(cz + k, GC - 1);
        const int ylo = max(cy - k, 0), yhi = min(cy + k, GC - 1);
        const int xlo = max(cx - k, 0), xhi = min(cx + k, GC - 1);
        int cid = 0;
        for (int z = zlo; z <= zhi; ++z)
            for (int y = ylo; y <= yhi; ++y)
                for (int xx = xlo; xx <= xhi; ++xx) {
                    const int cheb = max(max(abs(xx - cx), abs(y - cy)), abs(z - cz));
                    if (cheb <= prevk) continue;            // already scanned
                    const bool mine = ((cid & 7) == t8); ++cid;
                    if (!mine) continue;
                    const int cell = (z * GC + y) * GC + xx;
                    const int s0 = cs[cell], e0 = cs[cell + 1];
                    for (int i = s0; i < e0; ++i) {
                        const float4 P = cp[i];
                        const float dot2 = __fadd_rn(
                            __fadd_rn(__fmul_rn(q0, P.x), __fmul_rn(q1, P.y)),
                            __fmul_rn(q2, P.z));
                        const float d = __fsub_rn(__fadd_rn(qq, P.w), dot2);
                        const double kk = __longlong_as_double(
                            __double_as_longlong((double)d) | (long long)ci[i]);
                        INSERT3(kA, kB, kC, kk);
                    }
                }

        // butterfly merge of per-lane partials (disjoint lane sets -> no dup)
        mA = kA; mB = kB; mC = kC;
#pragma unroll
        for (int mask = 1; mask < 8; mask <<= 1) {
            const double pA = __shfl_xor(mA, mask, 8);
            const double pB = __shfl_xor(mB, mask, 8);
            const double pC = __shfl_xor(mC, mask, 8);
            INSERT3(mA, mB, mC, pA);
            INSERT3(mA, mB, mC, pB);
            INSERT3(mA, mB, mC, pC);
        }

        if (zlo == 0 && ylo == 0 && xlo == 0 &&
            zhi == GC - 1 && yhi == GC - 1 && xhi == GC - 1) break;  // all scanned

        // stop check: slab distance from q to scanned-box boundary (grid-edge
        // faces open -> conservative for clamped outliers)
        const float dC = (float)__longlong_as_double(
            __double_as_longlong(mC) & ~0x7FFll);        // INF if <3 found
        float rmin = 1e30f;
        if (cx - k > 0)      rmin = fminf(rmin, q0 - (GLO + (float)(cx - k) * GH));
        if (cx + k < GC - 1) rmin = fminf(rmin, (GLO + (float)(cx + k + 1) * GH) - q0);
        if (cy - k > 0)      rmin = fminf(rmin, q1 - (GLO + (float)(cy - k) * GH));
        if (cy + k < GC - 1) rmin = fminf(rmin, (GLO + (float)(cy + k + 1) * GH) - q1);
        if (cz - k > 0)      rmin = fminf(rmin, q2 - (GLO + (float)(cz - k) * GH));
        if (cz + k < GC - 1) rmin = fminf(rmin, (GLO + (float)(cz + k + 1) * GH) - q2);
        rmin = fmaxf(rmin, 0.0f);
        if (dC < rmin * rmin - 1e-4f) break;
        prevk = k; ++k;
    }

    if (t8 == 0) {
        const long long ba = __double_as_longlong(mA);
        const long long bb = __double_as_longlong(mB);
        const long long bc = __double_as_longlong(mC);
        const float dA = (float)__longlong_as_double(ba & ~0x7FFll);
        const float dB = (float)__longlong_as_double(bb & ~0x7FFll);
        const float dC = (float)__longlong_as_double(bc & ~0x7FFll);
        const float w0 = 1.0f / (fmaxf(dA, 0.0f) + 1e-16f);
        const float w1 = 1.0f / (fmaxf(dB, 0.0f) + 1e-16f);
        const float w2 = 1.0f / (fmaxf(dC, 0.0f) + 1e-16f);
        const float rden = 1.0f / (w0 + w1 + w2);
        rIdx[g][0] = (int)(ba & 0x7FF);
        rIdx[g][1] = (int)(bb & 0x7FF);
        rIdx[g][2] = (int)(bc & 0x7FF);
        rW[g][0] = w0 * rden; rW[g][1] = w1 * rden; rW[g][2] = w2 * rden;
    }
    __syncthreads();

    // gather: wave w handles queries [w*8, w*8+8); lane covers 4 channels
    const int wave = tid >> 6, lane = tid & 63;
    const size_t xbase = (size_t)b * Nn * CIN;
    for (int j = 0; j < 8; ++j) {
        const int lq = wave * 8 + j;
        const int gq = blockQ + lq;
        const int i0 = rIdx[lq][0], i1 = rIdx[lq][1], i2 = rIdx[lq][2];
        const float w0 = rW[lq][0], w1 = rW[lq][1], w2 = rW[lq][2];
        const float4 f0 = ((const float4*)(x + xbase + (size_t)i0 * CIN))[lane];
        const float4 f1 = ((const float4*)(x + xbase + (size_t)i1 * CIN))[lane];
        const float4 f2 = ((const float4*)(x + xbase + (size_t)i2 * CIN))[lane];
        ushort4 ov;
        ov.x = f2bf(fmaf(w2, f2.x, fmaf(w1, f1.x, w0 * f0.x)));
        ov.y = f2bf(fmaf(w2, f2.y, fmaf(w1, f1.y, w0 * f0.y)));
        ov.z = f2bf(fmaf(w2, f2.z, fmaf(w1, f1.z, w0 * f0.z)));
        ov.w = f2bf(fmaf(w2, f2.w, fmaf(w1, f1.w, w0 * f0.w)));
        *(ushort4*)(Abig + (size_t)gq * KTOT + lane * 4) = ov;
    }
}

// ---------------------------------------------------------------------------
// Kernel C: fused MLP via bf16 MFMA (32x32x16), f32 accum. (unchanged)
// ---------------------------------------------------------------------------
__global__ __launch_bounds__(256, 1) void mlp_fused(
    const ushort* __restrict__ Abig,   // [32768][384] bf16
    const ushort* __restrict__ W1T,    // [256][384] bf16
    const float*  __restrict__ b1,
    const ushort* __restrict__ W2T,    // [128][256] bf16
    const float*  __restrict__ b2,
    float* __restrict__ out)           // [32768][128] f32
{
    __shared__ ushort Ast[128 * 32];   // 8 KB
    __shared__ ushort Bst[128 * 32];   // 8 KB
    __shared__ ushort Hs [128 * 128];  // 32 KB

    const int tid  = threadIdx.x;
    const int wave = tid >> 6, lane = tid & 63;
    const int wr = wave >> 1, wc = wave & 1;      // 2x2 wave grid
    const int l31 = lane & 31, kc0 = lane >> 5;   // MFMA k-half
    const long rowbase = (long)blockIdx.x * 128;

    const int sr0 = tid >> 2;          // staging row (row+64 for 2nd chunk)
    const int ss0 = tid & 3;           // 16B slot
    const int ssw = (ss0 ^ (sr0 & 3)); // swizzled slot

    f32x16 acc2[2][2];
#pragma unroll
    for (int i = 0; i < 2; ++i)
#pragma unroll
        for (int j = 0; j < 2; ++j)
#pragma unroll
            for (int e = 0; e < 16; ++e) acc2[i][j][e] = 0.0f;

    for (int nh = 0; nh < 2; ++nh) {
        f32x16 acc1[2][2];
#pragma unroll
        for (int i = 0; i < 2; ++i)
#pragma unroll
            for (int j = 0; j < 2; ++j)
#pragma unroll
                for (int e = 0; e < 16; ++e) acc1[i][j][e] = 0.0f;

        const ushort* Ab = Abig + (size_t)rowbase * KTOT;
        const ushort* Wb = W1T + (size_t)(nh * 128) * KTOT;

        uint4 ra0, ra1, rb0, rb1;
        ra0 = *(const uint4*)(Ab + (size_t)sr0 * KTOT + ss0 * 8);
        ra1 = *(const uint4*)(Ab + (size_t)(sr0 + 64) * KTOT + ss0 * 8);
        rb0 = *(const uint4*)(Wb + (size_t)sr0 * KTOT + ss0 * 8);
        rb1 = *(const uint4*)(Wb + (size_t)(sr0 + 64) * KTOT + ss0 * 8);

        for (int t = 0; t < 12; ++t) {
            __syncthreads();
            *(uint4*)&Ast[sr0 * 32 + (ssw << 3)]        = ra0;
            *(uint4*)&Ast[(sr0 + 64) * 32 + (ssw << 3)] = ra1;
            *(uint4*)&Bst[sr0 * 32 + (ssw << 3)]        = rb0;
            *(uint4*)&Bst[(sr0 + 64) * 32 + (ssw << 3)] = rb1;
            __syncthreads();
            if (t < 11) {
                const int kt = (t + 1) * 32;
                ra0 = *(const uint4*)(Ab + (size_t)sr0 * KTOT + kt + ss0 * 8);
                ra1 = *(const uint4*)(Ab + (size_t)(sr0 + 64) * KTOT + kt + ss0 * 8);
                rb0 = *(const uint4*)(Wb + (size_t)sr0 * KTOT + kt + ss0 * 8);
                rb1 = *(const uint4*)(Wb + (size_t)(sr0 + 64) * KTOT + kt + ss0 * 8);
            }
#pragma unroll
            for (int s = 0; s < 2; ++s) {
                bf16x8 af[2], bq[2];
#pragma unroll
                for (int mf = 0; mf < 2; ++mf) {
                    const int r = wr * 64 + mf * 32 + l31;
                    af[mf] = *(const bf16x8*)&Ast[r * 32 + ((((s << 1) | kc0) ^ (r & 3)) << 3)];
                }
#pragma unroll
                for (int nf = 0; nf < 2; ++nf) {
                    const int rn = wc * 64 + nf * 32 + l31;
                    bq[nf] = *(const bf16x8*)&Bst[rn * 32 + ((((s << 1) | kc0) ^ (rn & 3)) << 3)];
                }
#pragma unroll
                for (int mf = 0; mf < 2; ++mf)
#pragma unroll
                    for (int nf = 0; nf < 2; ++nf)
                        acc1[mf][nf] = __builtin_amdgcn_mfma_f32_32x32x16_bf16(
                            af[mf], bq[nf], acc1[mf][nf], 0, 0, 0);
            }
        }

#pragma unroll
        for (int mf = 0; mf < 2; ++mf)
#pragma unroll
            for (int nf = 0; nf < 2; ++nf) {
                const int col = wc * 64 + nf * 32 + l31;
                const float b1v = b1[nh * 128 + col];
#pragma unroll
                for (int e = 0; e < 16; ++e) {
                    const int rl = wr * 64 + mf * 32 + (e & 3) + ((e >> 2) << 3) + (kc0 << 2);
                    const float hv = fmaxf(acc1[mf][nf][e] + b1v, 0.0f);
                    Hs[rl * 128 + (((col >> 3) ^ (rl & 7)) << 3) + (col & 7)] = f2bf(hv);
                }
            }
        __syncthreads();

        uint4 rw0, rw1;
        rw0 = *(const uint4*)(W2T + (size_t)sr0 * HID + nh * 128 + ss0 * 8);
        rw1 = *(const uint4*)(W2T + (size_t)(sr0 + 64) * HID + nh * 128 + ss0 * 8);

        for (int t = 0; t < 4; ++t) {
            __syncthreads();
            *(uint4*)&Bst[sr0 * 32 + (ssw << 3)]        = rw0;
            *(uint4*)&Bst[(sr0 + 64) * 32 + (ssw << 3)] = rw1;
            __syncthreads();
            if (t < 3) {
                const int kt = nh * 128 + (t + 1) * 32;
                rw0 = *(const uint4*)(W2T + (size_t)sr0 * HID + kt + ss0 * 8);
                rw1 = *(const uint4*)(W2T + (size_t)(sr0 + 64) * HID + kt + ss0 * 8);
            }
#pragma unroll
            for (int s = 0; s < 2; ++s) {
                bf16x8 af[2], bq[2];
#pragma unroll
                for (int mf = 0; mf < 2; ++mf) {
                    const int r  = wr * 64 + mf * 32 + l31;
                    const int kc = (t << 2) + (s << 1) + kc0;
                    af[mf] = *(const bf16x8*)&Hs[r * 128 + ((kc ^ (r & 7)) << 3)];
                }
#pragma unroll
                for (int nf = 0; nf < 2; ++nf) {
                    const int rn = wc * 64 + nf * 32 + l31;
                    bq[nf] = *(const bf16x8*)&Bst[rn * 32 + ((((s << 1) | kc0) ^ (rn & 3)) << 3)];
                }
#pragma unroll
                for (int mf = 0; mf < 2; ++mf)
#pragma unroll
                    for (int nf = 0; nf < 2; ++nf)
                        acc2[mf][nf] = __builtin_amdgcn_mfma_f32_32x32x16_bf16(
                            af[mf], bq[nf], acc2[mf][nf], 0, 0, 0);
            }
        }
        __syncthreads();
    }

#pragma unroll
    for (int mf = 0; mf < 2; ++mf)
#pragma unroll
        for (int nf = 0; nf < 2; ++nf) {
            const int col = wc * 64 + nf * 32 + l31;
            const float b2v = b2[col];
#pragma unroll
            for (int e = 0; e < 16; ++e) {
                const int rl = wr * 64 + mf * 32 + (e & 3) + ((e >> 2) << 3) + (kc0 << 2);
                out[(rowbase + rl) * COUT + col] = acc2[mf][nf][e] + b2v;
            }
        }
}

// ---------------------------------------------------------------------------
extern "C" void kernel_launch(void* const* d_in, const int* in_sizes, int n_in,
                              void* d_out, int out_size, void* d_ws, size_t ws_size,
                              hipStream_t stream)
{
    const float* x        = (const float*)d_in[0];
    const float* pos      = (const float*)d_in[1];
    const float* x_skip   = (const float*)d_in[2];
    const float* pos_skip = (const float*)d_in[3];
    const float* W1       = (const float*)d_in[4];
    const float* b1       = (const float*)d_in[5];
    const float* W2       = (const float*)d_in[6];
    const float* b2       = (const float*)d_in[7];

    float* out = (float*)d_out;

    // workspace: Abig | W1T | W2T | spos4 | sidx | cellStart | cnt  (~25.5 MB)
    char* wp = (char*)d_ws;
    ushort* Abig = (ushort*)wp;  wp += (size_t)Bn * Mn * KTOT * 2;   // 24 MB
    ushort* W1T  = (ushort*)wp;  wp += (size_t)HID * KTOT * 2;       // 192 KB
    ushort* W2T  = (ushort*)wp;  wp += (size_t)COUT * HID * 2;       // 64 KB
    float4* spos4 = (float4*)wp; wp += (size_t)Bn * Nn * 16;         // 128 KB
    int*    sidx  = (int*)wp;    wp += (size_t)Bn * Nn * 4;          // 32 KB
    int*    cellS = (int*)wp;    wp += (size_t)Bn * (NCC + 1) * 4;   // 512 KB
    int*    cnt   = (int*)wp;                                        // 512 KB

    // A) per-batch grid build (hist + prefix + scatter)
    build_grid<<<dim3(Bn), 512, 0, stream>>>(pos, spos4, sidx, cellS, cnt);

    // B) KNN shell-scan (1024 blocks, 8 thr/query) + converts + tail (4736)
    knn_gather<<<dim3(1024 + 4736), 256, 0, stream>>>(
        x, spos4, sidx, cellS, x_skip, pos_skip, W1, W2, Abig, W1T, W2T,
        out + (size_t)Bn * Mn * COUT);

    // C) fused MLP: out = (relu([xi|x_skip] @ W1 + b1)) @ W2 + b2
    mlp_fused<<<dim3(Bn * Mn / 128), 256, 0, stream>>>(
        Abig, W1T, b1, W2T, b2, out);
}

// Round 10
// 84.874 us; speedup vs baseline: 14.4990x; 14.4990x over previous
//
#include <hip/hip_runtime.h>
#include <math.h>
#include <stdint.h>

// Problem constants (FPModule: knn-interpolate + 2-layer MLP)
#define Bn    4
#define Nn    2048
#define Mn    8192
#define CIN   256
#define CSKIP 128
#define HID   256
#define COUT  128
#define KTOT  384   // CIN + CSKIP

typedef short bf16x8 __attribute__((ext_vector_type(8)));
typedef float f32x16 __attribute__((ext_vector_type(16)));

__device__ __forceinline__ ushort f2bf(float f) {
    union { float f; unsigned u; } v; v.f = f;
    return (ushort)((v.u + 0x7fffu + ((v.u >> 16) & 1u)) >> 16);   // RNE
}

// 5-op sorted-insert of key k into (kA <= kB <= kC), keeping 3 smallest.
// Order-independent: final triple = 3 smallest keys of the inserted multiset.
#define INSERT3(kA, kB, kC, k)            \
    do {                                  \
        const double _t = fmax(kA, k);    \
        kA = fmin(kA, k);                 \
        const double _u = fmax(kB, _t);   \
        kB = fmin(kB, _t);                \
        kC = fmin(kC, _u);                \
    } while (0)

// ---------------------------------------------------------------------------
// Kernel A: pack pos -> pos4 = (2px, 2py, 2pz, pp).  8192 points, 32 blocks.
// pp via explicit _rn ops (matches reference); 2x exact so inner-loop dot2 is
// bit-identical to 2*dot of the reference.
// ---------------------------------------------------------------------------
__global__ __launch_bounds__(256) void pack_pos4(
    const float* __restrict__ pos, float4* __restrict__ pos4)
{
    const int i = blockIdx.x * 256 + threadIdx.x;   // 0..8191
    const float* p = pos + (size_t)i * 3;
    const float p0 = p[0], p1 = p[1], p2 = p[2];
    const float pp = __fadd_rn(__fadd_rn(__fmul_rn(p0, p0), __fmul_rn(p1, p1)),
                               __fmul_rn(p2, p2));
    pos4[i] = make_float4(2.0f * p0, 2.0f * p1, 2.0f * p2, pp);
}

// ---------------------------------------------------------------------------
// Kernel B (fused mid): block roles by blockIdx.x:
//   [0,2048)      KNN: 16 queries/block, 16 chunks x 128 cands (R7 layout).
//                 Phase 1: first 32 cands/thread, branchless f64-key INSERT3.
//                 LDS exchange: tau(query) = min over 16 chunk-lanes of each
//                 lane's 3rd-best (any subset's 3rd-best >= union's 3rd-best
//                 >= final d3 -> tau is a SAFE threshold).
//                 Phase 2: remaining 96 cands: exact d (7 inst) + 1 cmp;
//                 pack+INSERT3 only when d <= tau (<= keeps d3 ties so the
//                 lowest-index rule still sees them).
//                 Final: per-query merge over 16 lane triples == R7 merge.
//                 key = double(d)|orig_idx == lex (d,idx) == top_k order;
//                 d bit-identical to reference (see pack_pos4).
//   [2048,6144)   Abig[:,256:384] = bf16(x_skip)
//   [6144,6240)   W1T[n][k] = bf16(W1[k][n])
//   [6240,6272)   W2T[n][k] = bf16(W2[k][n])
//   [6272,6784)   tail: copy pos_skip + synthesize batch_skip into d_out
// ---------------------------------------------------------------------------
__global__ __launch_bounds__(256) void fused_mid(
    const float* __restrict__ x,         // (B*N, CIN)
    const float4* __restrict__ pos4,     // (B*N) packed
    const float* __restrict__ xs,        // (B*M, CSKIP)
    const float* __restrict__ pos_skip,  // (B*M, 3)
    const float* __restrict__ W1, const float* __restrict__ W2,
    ushort* __restrict__ Abig,           // (B*M, KTOT) bf16
    ushort* __restrict__ W1T, ushort* __restrict__ W2T,
    float* __restrict__ tail_dst)        // d_out + B*M*COUT
{
    __shared__ double sKey[16][3][17];   // per-(chunk,slot,query) keys, 6.5 KB
    __shared__ float  sThr[16][17];      // per-(chunk,query) 3rd-best, 1.1 KB
    __shared__ int    sIdx[16][3];
    __shared__ float  sRW[16][3];        // premultiplied weights w_i/den

    const int bid = blockIdx.x;
    const int tid = threadIdx.x;

    if (bid >= 2048) {
        // ---------------- aux roles ----------------
        const int cb = bid - 2048;
        if (cb < 4096) {
            const int q   = cb * 256 + tid;        // quad over 32768x128
            const int row = q >> 5;
            const int cq  = (q & 31) * 4;
            const float4 v = *(const float4*)(xs + (size_t)row * CSKIP + cq);
            ushort4 o; o.x = f2bf(v.x); o.y = f2bf(v.y); o.z = f2bf(v.z); o.w = f2bf(v.w);
            *(ushort4*)(Abig + (size_t)row * KTOT + CIN + cq) = o;
        } else if (cb < 4192) {
            const int q  = (cb - 4096) * 256 + tid;   // 24576 quads: n*96 + kq
            const int n  = q / 96;
            const int kq = (q % 96) * 4;
            ushort4 o;
            o.x = f2bf(W1[(size_t)(kq + 0) * HID + n]);
            o.y = f2bf(W1[(size_t)(kq + 1) * HID + n]);
            o.z = f2bf(W1[(size_t)(kq + 2) * HID + n]);
            o.w = f2bf(W1[(size_t)(kq + 3) * HID + n]);
            *(ushort4*)(W1T + (size_t)n * KTOT + kq) = o;
        } else if (cb < 4224) {
            const int q  = (cb - 4192) * 256 + tid;   // 8192 quads: n*64 + kq
            const int n  = q >> 6;
            const int kq = (q & 63) * 4;
            ushort4 o;
            o.x = f2bf(W2[(size_t)(kq + 0) * COUT + n]);
            o.y = f2bf(W2[(size_t)(kq + 1) * COUT + n]);
            o.z = f2bf(W2[(size_t)(kq + 2) * COUT + n]);
            o.w = f2bf(W2[(size_t)(kq + 3) * COUT + n]);
            *(ushort4*)(W2T + (size_t)n * HID + kq) = o;
        } else {
            const int i = (cb - 4224) * 256 + tid;
            const int nPos = Bn * Mn * 3;             // 98304
            if (i < nPos) tail_dst[i] = pos_skip[i];
            else          tail_dst[i] = (float)((i - nPos) >> 13);
        }
        return;
    }

    // ---------------- KNN role ----------------
    const int qloc   = tid & 15;
    const int chunk  = tid >> 4;         // 0..15, 128 candidates each
    const int blockQ = bid * 16;
    const int b      = blockQ / Mn;      // uniform (512 blocks per batch)

    const int q = blockQ + qloc;
    const float* qp = pos_skip + (size_t)q * 3;
    const float q0 = qp[0], q1 = qp[1], q2 = qp[2];
    const float qq = __fadd_rn(__fadd_rn(__fmul_rn(q0, q0), __fmul_rn(q1, q1)),
                               __fmul_rn(q2, q2));

    const int base = chunk * 128;
    const float4* __restrict__ cp = pos4 + (size_t)b * Nn + base;

    double kA = (double)INFINITY, kB = (double)INFINITY, kC = (double)INFINITY;

    // ---- phase 1: first 32 candidates, branchless insert ----
#pragma unroll 4
    for (int j = 0; j < 32; ++j) {
        const float4 P = cp[j];
        const float dot2 = __fadd_rn(__fadd_rn(__fmul_rn(q0, P.x), __fmul_rn(q1, P.y)),
                                     __fmul_rn(q2, P.z));
        const float d = __fsub_rn(__fadd_rn(qq, P.w), dot2);
        const double k = __longlong_as_double(
            __double_as_longlong((double)d) | (long long)(base + j));
        INSERT3(kA, kB, kC, k);
    }
    // publish 3rd-best (idx bits cleared -> exact f32 d value)
    sThr[chunk][qloc] = (float)__longlong_as_double(
        __double_as_longlong(kC) & ~0x7FFll);
    __syncthreads();

    // tau = min over the 16 chunk-lanes' 3rd-best: every subset's 3rd-best
    // >= union 3rd-best >= FINAL d3  ->  safe filter threshold.
    float tau = sThr[0][qloc];
#pragma unroll
    for (int c = 1; c < 16; ++c) tau = fminf(tau, sThr[c][qloc]);

    // ---- phase 2: remaining 96 candidates, threshold-gated insert ----
#pragma unroll 4
    for (int j = 32; j < 128; ++j) {
        const float4 P = cp[j];
        const float dot2 = __fadd_rn(__fadd_rn(__fmul_rn(q0, P.x), __fmul_rn(q1, P.y)),
                                     __fmul_rn(q2, P.z));
        const float d = __fsub_rn(__fadd_rn(qq, P.w), dot2);
        if (d <= tau) {                  // rare after warm threshold
            const double k = __longlong_as_double(
                __double_as_longlong((double)d) | (long long)(base + j));
            INSERT3(kA, kB, kC, k);
        }
    }
    sKey[chunk][0][qloc] = kA;
    sKey[chunk][1][qloc] = kB;
    sKey[chunk][2][qloc] = kC;
    __syncthreads();

    // ---- merge 16 lane-triples per query (threads 0..15) ----
    if (tid < 16) {
        double mA = (double)INFINITY, mB = (double)INFINITY, mC = (double)INFINITY;
#pragma unroll
        for (int c = 0; c < 16; ++c)
#pragma unroll
            for (int s = 0; s < 3; ++s) {
                const double k = sKey[c][s][tid];
                INSERT3(mA, mB, mC, k);
            }
        const long long ba = __double_as_longlong(mA);
        const long long bb = __double_as_longlong(mB);
        const long long bc = __double_as_longlong(mC);
        const float dA = (float)__longlong_as_double(ba & ~0x7FFll);
        const float dB = (float)__longlong_as_double(bb & ~0x7FFll);
        const float dC = (float)__longlong_as_double(bc & ~0x7FFll);
        const float w0 = 1.0f / (fmaxf(dA, 0.0f) + 1e-16f);
        const float w1 = 1.0f / (fmaxf(dB, 0.0f) + 1e-16f);
        const float w2 = 1.0f / (fmaxf(dC, 0.0f) + 1e-16f);
        const float rden = 1.0f / (w0 + w1 + w2);
        sIdx[tid][0] = (int)(ba & 0x7FF);
        sIdx[tid][1] = (int)(bb & 0x7FF);
        sIdx[tid][2] = (int)(bc & 0x7FF);
        sRW[tid][0] = w0 * rden; sRW[tid][1] = w1 * rden; sRW[tid][2] = w2 * rden;
    }
    __syncthreads();

    // gather: wave w handles queries [w*4, w*4+4); lane covers 4 channels
    const int wave = tid >> 6, lane = tid & 63;
    const size_t xbase = (size_t)b * Nn * CIN;
    for (int j = 0; j < 4; ++j) {
        const int lq = wave * 4 + j;
        const int gq = blockQ + lq;
        const int i0 = sIdx[lq][0], i1 = sIdx[lq][1], i2 = sIdx[lq][2];
        const float w0 = sRW[lq][0], w1 = sRW[lq][1], w2 = sRW[lq][2];
        const float4 f0 = ((const float4*)(x + xbase + (size_t)i0 * CIN))[lane];
        const float4 f1 = ((const float4*)(x + xbase + (size_t)i1 * CIN))[lane];
        const float4 f2 = ((const float4*)(x + xbase + (size_t)i2 * CIN))[lane];
        ushort4 ov;
        ov.x = f2bf(fmaf(w2, f2.x, fmaf(w1, f1.x, w0 * f0.x)));
        ov.y = f2bf(fmaf(w2, f2.y, fmaf(w1, f1.y, w0 * f0.y)));
        ov.z = f2bf(fmaf(w2, f2.z, fmaf(w1, f1.z, w0 * f0.z)));
        ov.w = f2bf(fmaf(w2, f2.w, fmaf(w1, f1.w, w0 * f0.w)));
        *(ushort4*)(Abig + (size_t)gq * KTOT + lane * 4) = ov;
    }
}

// ---------------------------------------------------------------------------
// Kernel C: fused MLP via bf16 MFMA (32x32x16), f32 accum. (unchanged)
// ---------------------------------------------------------------------------
__global__ __launch_bounds__(256, 1) void mlp_fused(
    const ushort* __restrict__ Abig,   // [32768][384] bf16
    const ushort* __restrict__ W1T,    // [256][384] bf16
    const float*  __restrict__ b1,
    const ushort* __restrict__ W2T,    // [128][256] bf16
    const float*  __restrict__ b2,
    float* __restrict__ out)           // [32768][128] f32
{
    __shared__ ushort Ast[128 * 32];   // 8 KB
    __shared__ ushort Bst[128 * 32];   // 8 KB
    __shared__ ushort Hs [128 * 128];  // 32 KB

    const int tid  = threadIdx.x;
    const int wave = tid >> 6, lane = tid & 63;
    const int wr = wave >> 1, wc = wave & 1;      // 2x2 wave grid
    const int l31 = lane & 31, kc0 = lane >> 5;   // MFMA k-half
    const long rowbase = (long)blockIdx.x * 128;

    const int sr0 = tid >> 2;          // staging row (row+64 for 2nd chunk)
    const int ss0 = tid & 3;           // 16B slot
    const int ssw = (ss0 ^ (sr0 & 3)); // swizzled slot

    f32x16 acc2[2][2];
#pragma unroll
    for (int i = 0; i < 2; ++i)
#pragma unroll
        for (int j = 0; j < 2; ++j)
#pragma unroll
            for (int e = 0; e < 16; ++e) acc2[i][j][e] = 0.0f;

    for (int nh = 0; nh < 2; ++nh) {
        f32x16 acc1[2][2];
#pragma unroll
        for (int i = 0; i < 2; ++i)
#pragma unroll
            for (int j = 0; j < 2; ++j)
#pragma unroll
                for (int e = 0; e < 16; ++e) acc1[i][j][e] = 0.0f;

        const ushort* Ab = Abig + (size_t)rowbase * KTOT;
        const ushort* Wb = W1T + (size_t)(nh * 128) * KTOT;

        uint4 ra0, ra1, rb0, rb1;
        ra0 = *(const uint4*)(Ab + (size_t)sr0 * KTOT + ss0 * 8);
        ra1 = *(const uint4*)(Ab + (size_t)(sr0 + 64) * KTOT + ss0 * 8);
        rb0 = *(const uint4*)(Wb + (size_t)sr0 * KTOT + ss0 * 8);
        rb1 = *(const uint4*)(Wb + (size_t)(sr0 + 64) * KTOT + ss0 * 8);

        for (int t = 0; t < 12; ++t) {
            __syncthreads();
            *(uint4*)&Ast[sr0 * 32 + (ssw << 3)]        = ra0;
            *(uint4*)&Ast[(sr0 + 64) * 32 + (ssw << 3)] = ra1;
            *(uint4*)&Bst[sr0 * 32 + (ssw << 3)]        = rb0;
            *(uint4*)&Bst[(sr0 + 64) * 32 + (ssw << 3)] = rb1;
            __syncthreads();
            if (t < 11) {
                const int kt = (t + 1) * 32;
                ra0 = *(const uint4*)(Ab + (size_t)sr0 * KTOT + kt + ss0 * 8);
                ra1 = *(const uint4*)(Ab + (size_t)(sr0 + 64) * KTOT + kt + ss0 * 8);
                rb0 = *(const uint4*)(Wb + (size_t)sr0 * KTOT + kt + ss0 * 8);
                rb1 = *(const uint4*)(Wb + (size_t)(sr0 + 64) * KTOT + kt + ss0 * 8);
            }
#pragma unroll
            for (int s = 0; s < 2; ++s) {
                bf16x8 af[2], bq[2];
#pragma unroll
                for (int mf = 0; mf < 2; ++mf) {
                    const int r = wr * 64 + mf * 32 + l31;
                    af[mf] = *(const bf16x8*)&Ast[r * 32 + ((((s << 1) | kc0) ^ (r & 3)) << 3)];
                }
#pragma unroll
                for (int nf = 0; nf < 2; ++nf) {
                    const int rn = wc * 64 + nf * 32 + l31;
                    bq[nf] = *(const bf16x8*)&Bst[rn * 32 + ((((s << 1) | kc0) ^ (rn & 3)) << 3)];
                }
#pragma unroll
                for (int mf = 0; mf < 2; ++mf)
#pragma unroll
                    for (int nf = 0; nf < 2; ++nf)
                        acc1[mf][nf] = __builtin_amdgcn_mfma_f32_32x32x16_bf16(
                            af[mf], bq[nf], acc1[mf][nf], 0, 0, 0);
            }
        }

#pragma unroll
        for (int mf = 0; mf < 2; ++mf)
#pragma unroll
            for (int nf = 0; nf < 2; ++nf) {
                const int col = wc * 64 + nf * 32 + l31;
                const float b1v = b1[nh * 128 + col];
#pragma unroll
                for (int e = 0; e < 16; ++e) {
                    const int rl = wr * 64 + mf * 32 + (e & 3) + ((e >> 2) << 3) + (kc0 << 2);
                    const float hv = fmaxf(acc1[mf][nf][e] + b1v, 0.0f);
                    Hs[rl * 128 + (((col >> 3) ^ (rl & 7)) << 3) + (col & 7)] = f2bf(hv);
                }
            }
        __syncthreads();

        uint4 rw0, rw1;
        rw0 = *(const uint4*)(W2T + (size_t)sr0 * HID + nh * 128 + ss0 * 8);
        rw1 = *(const uint4*)(W2T + (size_t)(sr0 + 64) * HID + nh * 128 + ss0 * 8);

        for (int t = 0; t < 4; ++t) {
            __syncthreads();
            *(uint4*)&Bst[sr0 * 32 + (ssw << 3)]        = rw0;
            *(uint4*)&Bst[(sr0 + 64) * 32 + (ssw << 3)] = rw1;
            __syncthreads();
            if (t < 3) {
                const int kt = nh * 128 + (t + 1) * 32;
                rw0 = *(const uint4*)(W2T + (size_t)sr0 * HID + kt + ss0 * 8);
                rw1 = *(const uint4*)(W2T + (size_t)(sr0 + 64) * HID + kt + ss0 * 8);
            }
#pragma unroll
            for (int s = 0; s < 2; ++s) {
                bf16x8 af[2], bq[2];
#pragma unroll
                for (int mf = 0; mf < 2; ++mf) {
                    const int r  = wr * 64 + mf * 32 + l31;
                    const int kc = (t << 2) + (s << 1) + kc0;
                    af[mf] = *(const bf16x8*)&Hs[r * 128 + ((kc ^ (r & 7)) << 3)];
                }
#pragma unroll
                for (int nf = 0; nf < 2; ++nf) {
                    const int rn = wc * 64 + nf * 32 + l31;
                    bq[nf] = *(const bf16x8*)&Bst[rn * 32 + ((((s << 1) | kc0) ^ (rn & 3)) << 3)];
                }
#pragma unroll
                for (int mf = 0; mf < 2; ++mf)
#pragma unroll
                    for (int nf = 0; nf < 2; ++nf)
                        acc2[mf][nf] = __builtin_amdgcn_mfma_f32_32x32x16_bf16(
                            af[mf], bq[nf], acc2[mf][nf], 0, 0, 0);
            }
        }
        __syncthreads();
    }

#pragma unroll
    for (int mf = 0; mf < 2; ++mf)
#pragma unroll
        for (int nf = 0; nf < 2; ++nf) {
            const int col = wc * 64 + nf * 32 + l31;
            const float b2v = b2[col];
#pragma unroll
            for (int e = 0; e < 16; ++e) {
                const int rl = wr * 64 + mf * 32 + (e & 3) + ((e >> 2) << 3) + (kc0 << 2);
                out[(rowbase + rl) * COUT + col] = acc2[mf][nf][e] + b2v;
            }
        }
}

// ---------------------------------------------------------------------------
extern "C" void kernel_launch(void* const* d_in, const int* in_sizes, int n_in,
                              void* d_out, int out_size, void* d_ws, size_t ws_size,
                              hipStream_t stream)
{
    const float* x        = (const float*)d_in[0];
    const float* pos      = (const float*)d_in[1];
    const float* x_skip   = (const float*)d_in[2];
    const float* pos_skip = (const float*)d_in[3];
    const float* W1       = (const float*)d_in[4];
    const float* b1       = (const float*)d_in[5];
    const float* W2       = (const float*)d_in[6];
    const float* b2       = (const float*)d_in[7];

    float* out = (float*)d_out;

    // workspace: Abig (24MB) | W1T (192KB) | W2T (64KB) | pos4 (128KB)
    ushort* Abig = (ushort*)d_ws;
    ushort* W1T  = (ushort*)((char*)d_ws + (size_t)Bn * Mn * KTOT * 2);
    ushort* W2T  = (ushort*)((char*)W1T + (size_t)HID * KTOT * 2);
    float4* pos4 = (float4*)((char*)W2T + (size_t)COUT * HID * 2);

    // A) pack pos -> (2px,2py,2pz,pp)
    pack_pos4<<<dim3(Bn * Nn / 256), 256, 0, stream>>>(pos, pos4);

    // B) KNN (2048 blocks, threshold-gated) + converts + tail (4736 blocks)
    fused_mid<<<dim3(2048 + 4736), 256, 0, stream>>>(
        x, pos4, x_skip, pos_skip, W1, W2, Abig, W1T, W2T,
        out + (size_t)Bn * Mn * COUT);

    // C) fused MLP: out = (relu([xi|x_skip] @ W1 + b1)) @ W2 + b2
    mlp_fused<<<dim3(Bn * Mn / 128), 256, 0, stream>>>(
        Abig, W1T, b1, W2T, b2, out);
}

// Round 11
// 77.792 us; speedup vs baseline: 15.8189x; 1.0910x over previous
//
#include <hip/hip_runtime.h>
#include <math.h>
#include <stdint.h>

// Problem constants (FPModule: knn-interpolate + 2-layer MLP)
#define Bn    4
#define Nn    2048
#define Mn    8192
#define CIN   256
#define CSKIP 128
#define HID   256
#define COUT  128
#define KTOT  384   // CIN + CSKIP

typedef short bf16x8 __attribute__((ext_vector_type(8)));
typedef float f32x16 __attribute__((ext_vector_type(16)));

__device__ __forceinline__ ushort f2bf(float f) {
    union { float f; unsigned u; } v; v.f = f;
    return (ushort)((v.u + 0x7fffu + ((v.u >> 16) & 1u)) >> 16);   // RNE
}
__device__ __forceinline__ float bf2f(ushort u) {
    union { unsigned u; float f; } v; v.u = ((unsigned)u) << 16;
    return v.f;
}

// 5-op sorted-insert of key k into (kA <= kB <= kC), keeping 3 smallest.
#define INSERT3(kA, kB, kC, k)            \
    do {                                  \
        const double _t = fmax(kA, k);    \
        kA = fmin(kA, k);                 \
        const double _u = fmax(kB, _t);   \
        kB = fmin(kB, _t);                \
        kC = fmin(kC, _u);                \
    } while (0)

// ---------------------------------------------------------------------------
// Kernel 1: prep — all bf16 converts + pos4 pack + tail outputs.
//   [0,2048)      xb  = bf16(x)        (8192 x 256)
//   [2048,6144)   xsb = bf16(x_skip)   (32768 x 128)
//   [6144,6240)   W1T[n][k] = bf16(W1[k][n])   (256 x 384)
//   [6240,6272)   W2T[n][k] = bf16(W2[k][n])   (128 x 256)
//   [6272,6304)   pos4 = (2px,2py,2pz,pp)  — pp via _rn ops; 2x exact so the
//                 query-side dot2 is bit-identical to 2*dot of the reference
//   [6304,6816)   tail: copy pos_skip + synthesize batch_skip into d_out
// ---------------------------------------------------------------------------
__global__ __launch_bounds__(256) void prep_kernel(
    const float* __restrict__ x, const float* __restrict__ xs,
    const float* __restrict__ pos, const float* __restrict__ pos_skip,
    const float* __restrict__ W1, const float* __restrict__ W2,
    ushort* __restrict__ xb, ushort* __restrict__ xsb,
    ushort* __restrict__ W1T, ushort* __restrict__ W2T,
    float4* __restrict__ pos4, float* __restrict__ tail_dst)
{
    const int bid = blockIdx.x, tid = threadIdx.x;
    if (bid < 2048) {
        const int q   = bid * 256 + tid;           // quads over 8192x256
        const int row = q >> 6;
        const int cq  = (q & 63) * 4;
        const float4 v = *(const float4*)(x + (size_t)row * CIN + cq);
        ushort4 o; o.x = f2bf(v.x); o.y = f2bf(v.y); o.z = f2bf(v.z); o.w = f2bf(v.w);
        *(ushort4*)(xb + (size_t)row * CIN + cq) = o;
    } else if (bid < 6144) {
        const int q   = (bid - 2048) * 256 + tid;  // quads over 32768x128
        const int row = q >> 5;
        const int cq  = (q & 31) * 4;
        const float4 v = *(const float4*)(xs + (size_t)row * CSKIP + cq);
        ushort4 o; o.x = f2bf(v.x); o.y = f2bf(v.y); o.z = f2bf(v.z); o.w = f2bf(v.w);
        *(ushort4*)(xsb + (size_t)row * CSKIP + cq) = o;
    } else if (bid < 6240) {
        const int q  = (bid - 6144) * 256 + tid;   // 24576 quads: n*96 + kq
        const int n  = q / 96;
        const int kq = (q % 96) * 4;
        ushort4 o;
        o.x = f2bf(W1[(size_t)(kq + 0) * HID + n]);
        o.y = f2bf(W1[(size_t)(kq + 1) * HID + n]);
        o.z = f2bf(W1[(size_t)(kq + 2) * HID + n]);
        o.w = f2bf(W1[(size_t)(kq + 3) * HID + n]);
        *(ushort4*)(W1T + (size_t)n * KTOT + kq) = o;
    } else if (bid < 6272) {
        const int q  = (bid - 6240) * 256 + tid;   // 8192 quads: n*64 + kq
        const int n  = q >> 6;
        const int kq = (q & 63) * 4;
        ushort4 o;
        o.x = f2bf(W2[(size_t)(kq + 0) * COUT + n]);
        o.y = f2bf(W2[(size_t)(kq + 1) * COUT + n]);
        o.z = f2bf(W2[(size_t)(kq + 2) * COUT + n]);
        o.w = f2bf(W2[(size_t)(kq + 3) * COUT + n]);
        *(ushort4*)(W2T + (size_t)n * HID + kq) = o;
    } else if (bid < 6304) {
        const int i = (bid - 6272) * 256 + tid;    // 0..8191
        const float* p = pos + (size_t)i * 3;
        const float p0 = p[0], p1 = p[1], p2 = p[2];
        const float pp = __fadd_rn(__fadd_rn(__fmul_rn(p0, p0), __fmul_rn(p1, p1)),
                                   __fmul_rn(p2, p2));
        pos4[i] = make_float4(2.0f * p0, 2.0f * p1, 2.0f * p2, pp);
    } else {
        const int i = (bid - 6304) * 256 + tid;
        const int nPos = Bn * Mn * 3;              // 98304
        if (i < nPos) tail_dst[i] = pos_skip[i];
        else          tail_dst[i] = (float)((i - nPos) >> 13);
    }
}

// ---------------------------------------------------------------------------
// Shared 128x128 bf16 MFMA tile: acc += A[rowbase:+128, :32*ksteps] @ BT^T.
// A row-major [*, lda] bf16; BT row-major [N=128 rows at colbase, ldb] bf16.
// 256 threads, 2x2 waves, 8x mfma 32x32x16 per 32-wide k-step.
// ---------------------------------------------------------------------------
__device__ __forceinline__ void gemm_acc128(
    const ushort* __restrict__ A, int lda,
    const ushort* __restrict__ BT, int ldb,
    int ksteps, long rowbase, long colbase, int tid,
    ushort* Ast, ushort* Bst, f32x16 acc[2][2])
{
    const int wave = tid >> 6, lane = tid & 63;
    const int wr = wave >> 1, wc = wave & 1;
    const int l31 = lane & 31, kc0 = lane >> 5;
    const int sr0 = tid >> 2;
    const int ss0 = tid & 3;
    const int ssw = ss0 ^ (sr0 & 3);

    uint4 ra0, ra1, rb0, rb1;
    ra0 = *(const uint4*)(A + (rowbase + sr0) * lda + ss0 * 8);
    ra1 = *(const uint4*)(A + (rowbase + sr0 + 64) * lda + ss0 * 8);
    rb0 = *(const uint4*)(BT + (colbase + sr0) * ldb + ss0 * 8);
    rb1 = *(const uint4*)(BT + (colbase + sr0 + 64) * ldb + ss0 * 8);

    for (int t = 0; t < ksteps; ++t) {
        __syncthreads();
        *(uint4*)&Ast[sr0 * 32 + (ssw << 3)]        = ra0;
        *(uint4*)&Ast[(sr0 + 64) * 32 + (ssw << 3)] = ra1;
        *(uint4*)&Bst[sr0 * 32 + (ssw << 3)]        = rb0;
        *(uint4*)&Bst[(sr0 + 64) * 32 + (ssw << 3)] = rb1;
        __syncthreads();
        if (t < ksteps - 1) {
            const int kt = (t + 1) * 32;
            ra0 = *(const uint4*)(A + (rowbase + sr0) * lda + kt + ss0 * 8);
            ra1 = *(const uint4*)(A + (rowbase + sr0 + 64) * lda + kt + ss0 * 8);
            rb0 = *(const uint4*)(BT + (colbase + sr0) * ldb + kt + ss0 * 8);
            rb1 = *(const uint4*)(BT + (colbase + sr0 + 64) * ldb + kt + ss0 * 8);
        }
#pragma unroll
        for (int s = 0; s < 2; ++s) {
            bf16x8 af[2], bq[2];
#pragma unroll
            for (int mf = 0; mf < 2; ++mf) {
                const int r = wr * 64 + mf * 32 + l31;
                af[mf] = *(const bf16x8*)&Ast[r * 32 + ((((s << 1) | kc0) ^ (r & 3)) << 3)];
            }
#pragma unroll
            for (int nf = 0; nf < 2; ++nf) {
                const int rn = wc * 64 + nf * 32 + l31;
                bq[nf] = *(const bf16x8*)&Bst[rn * 32 + ((((s << 1) | kc0) ^ (rn & 3)) << 3)];
            }
#pragma unroll
            for (int mf = 0; mf < 2; ++mf)
#pragma unroll
                for (int nf = 0; nf < 2; ++nf)
                    acc[mf][nf] = __builtin_amdgcn_mfma_f32_32x32x16_bf16(
                        af[mf], bq[nf], acc[mf][nf], 0, 0, 0);
        }
    }
}

// ---------------------------------------------------------------------------
// Kernel 2: Y = xb @ W1[:256]  (8192x256, grid part [0,128))
//           Z = xsb @ W1[256:] (32768x256, grid part [128,640))
// bf16 outputs (rounding absorbed by bf16 tolerance).
// ---------------------------------------------------------------------------
__global__ __launch_bounds__(256) void yz_gemm(
    const ushort* __restrict__ xb, const ushort* __restrict__ xsb,
    const ushort* __restrict__ W1T,
    ushort* __restrict__ Y, ushort* __restrict__ Z)
{
    __shared__ ushort Ast[128 * 32];
    __shared__ ushort Bst[128 * 32];

    const int bid = blockIdx.x, tid = threadIdx.x;
    f32x16 acc[2][2];
#pragma unroll
    for (int i = 0; i < 2; ++i)
#pragma unroll
        for (int j = 0; j < 2; ++j)
#pragma unroll
            for (int e = 0; e < 16; ++e) acc[i][j][e] = 0.0f;

    const ushort* A; ushort* C;
    long rowbase, colbase; int lda, ksteps; const ushort* BT; int ldb = KTOT;
    if (bid < 128) {                     // Y role
        rowbase = (long)(bid >> 1) * 128; colbase = (long)(bid & 1) * 128;
        A = xb; lda = CIN; ksteps = CIN / 32; BT = W1T; C = Y;
    } else {                             // Z role
        const int cb = bid - 128;
        rowbase = (long)(cb >> 1) * 128; colbase = (long)(cb & 1) * 128;
        A = xsb; lda = CSKIP; ksteps = CSKIP / 32; BT = W1T + CIN; C = Z;
    }
    gemm_acc128(A, lda, BT, ldb, ksteps, rowbase, colbase, tid, Ast, Bst, acc);

    const int wave = tid >> 6, lane = tid & 63;
    const int wr = wave >> 1, wc = wave & 1;
    const int l31 = lane & 31, kc0 = lane >> 5;
#pragma unroll
    for (int mf = 0; mf < 2; ++mf)
#pragma unroll
        for (int nf = 0; nf < 2; ++nf) {
            const long col = colbase + wc * 64 + nf * 32 + l31;
#pragma unroll
            for (int e = 0; e < 16; ++e) {
                const int rl = wr * 64 + mf * 32 + (e & 3) + ((e >> 2) << 3) + (kc0 << 2);
                C[(rowbase + rl) * HID + col] = f2bf(acc[mf][nf][e]);
            }
        }
}

// ---------------------------------------------------------------------------
// Kernel 3: KNN select (R7-exact, bit-identical selection) + fused h-build.
// 2048 blocks: 16 queries/block, 16 chunks x 128 cands, branchless f64-key
// (key = double(d) | orig_idx in low 11 mantissa bits == lex (d,idx) ==
// top_k value-then-lowest-index; d bit-identical to reference via pos4).
// h[q] = relu(w0*Y[i0] + w1*Y[i1] + w2*Y[i2] + Z[q] + b1)  (bf16 out).
// ---------------------------------------------------------------------------
__global__ __launch_bounds__(256) void knn_h(
    const float4* __restrict__ pos4,     // (B*N) packed
    const float* __restrict__ pos_skip,  // (B*M, 3)
    const ushort* __restrict__ Y,        // (B*N, HID) bf16
    const ushort* __restrict__ Z,        // (B*M, HID) bf16
    const float* __restrict__ b1,        // (HID)
    ushort* __restrict__ h)              // (B*M, HID) bf16 out
{
    __shared__ double sKey[16][3][17];
    __shared__ int    sIdx[16][3];
    __shared__ float  sRW[16][3];

    const int tid    = threadIdx.x;
    const int qloc   = tid & 15;
    const int chunk  = tid >> 4;
    const int blockQ = blockIdx.x * 16;
    const int b      = blockQ / Mn;

    const int q = blockQ + qloc;
    const float* qp = pos_skip + (size_t)q * 3;
    const float q0 = qp[0], q1 = qp[1], q2 = qp[2];
    const float qq = __fadd_rn(__fadd_rn(__fmul_rn(q0, q0), __fmul_rn(q1, q1)),
                               __fmul_rn(q2, q2));

    const int base = chunk * 128;
    const float4* __restrict__ cp = pos4 + (size_t)b * Nn + base;

    double kA = (double)INFINITY, kB = (double)INFINITY, kC = (double)INFINITY;
#pragma unroll 4
    for (int j = 0; j < 128; ++j) {
        const float4 P = cp[j];
        const float dot2 = __fadd_rn(__fadd_rn(__fmul_rn(q0, P.x), __fmul_rn(q1, P.y)),
                                     __fmul_rn(q2, P.z));
        const float d = __fsub_rn(__fadd_rn(qq, P.w), dot2);
        const double k = __longlong_as_double(
            __double_as_longlong((double)d) | (long long)(base + j));
        INSERT3(kA, kB, kC, k);
    }
    sKey[chunk][0][qloc] = kA;
    sKey[chunk][1][qloc] = kB;
    sKey[chunk][2][qloc] = kC;
    __syncthreads();

    if (tid < 16) {
        double mA = (double)INFINITY, mB = (double)INFINITY, mC = (double)INFINITY;
#pragma unroll
        for (int c = 0; c < 16; ++c)
#pragma unroll
            for (int s = 0; s < 3; ++s) {
                const double k = sKey[c][s][tid];
                INSERT3(mA, mB, mC, k);
            }
        const long long ba = __double_as_longlong(mA);
        const long long bb = __double_as_longlong(mB);
        const long long bc = __double_as_longlong(mC);
        const float dA = (float)__longlong_as_double(ba & ~0x7FFll);
        const float dB = (float)__longlong_as_double(bb & ~0x7FFll);
        const float dC = (float)__longlong_as_double(bc & ~0x7FFll);
        const float w0 = 1.0f / (fmaxf(dA, 0.0f) + 1e-16f);
        const float w1 = 1.0f / (fmaxf(dB, 0.0f) + 1e-16f);
        const float w2 = 1.0f / (fmaxf(dC, 0.0f) + 1e-16f);
        const float rden = 1.0f / (w0 + w1 + w2);
        sIdx[tid][0] = (int)(ba & 0x7FF);
        sIdx[tid][1] = (int)(bb & 0x7FF);
        sIdx[tid][2] = (int)(bc & 0x7FF);
        sRW[tid][0] = w0 * rden; sRW[tid][1] = w1 * rden; sRW[tid][2] = w2 * rden;
    }
    __syncthreads();

    // h-build: wave w handles queries [w*4, w*4+4); lane covers 4 channels
    const int wave = tid >> 6, lane = tid & 63;
    const size_t ybase = (size_t)b * Nn;
    const float4 b1v = ((const float4*)b1)[lane];
    for (int j = 0; j < 4; ++j) {
        const int lq = wave * 4 + j;
        const int gq = blockQ + lq;
        const int i0 = sIdx[lq][0], i1 = sIdx[lq][1], i2 = sIdx[lq][2];
        const float w0 = sRW[lq][0], w1 = sRW[lq][1], w2 = sRW[lq][2];
        const ushort4 y0 = ((const ushort4*)(Y + (ybase + i0) * HID))[lane];
        const ushort4 y1 = ((const ushort4*)(Y + (ybase + i1) * HID))[lane];
        const ushort4 y2 = ((const ushort4*)(Y + (ybase + i2) * HID))[lane];
        const ushort4 zz = ((const ushort4*)(Z + (size_t)gq * HID))[lane];
        ushort4 ov;
        {
            float v;
            v = fmaf(w2, bf2f(y2.x), fmaf(w1, bf2f(y1.x), w0 * bf2f(y0.x))) + bf2f(zz.x) + b1v.x;
            ov.x = f2bf(fmaxf(v, 0.0f));
            v = fmaf(w2, bf2f(y2.y), fmaf(w1, bf2f(y1.y), w0 * bf2f(y0.y))) + bf2f(zz.y) + b1v.y;
            ov.y = f2bf(fmaxf(v, 0.0f));
            v = fmaf(w2, bf2f(y2.z), fmaf(w1, bf2f(y1.z), w0 * bf2f(y0.z))) + bf2f(zz.z) + b1v.z;
            ov.z = f2bf(fmaxf(v, 0.0f));
            v = fmaf(w2, bf2f(y2.w), fmaf(w1, bf2f(y1.w), w0 * bf2f(y0.w))) + bf2f(zz.w) + b1v.w;
            ov.w = f2bf(fmaxf(v, 0.0f));
        }
        *(ushort4*)(h + (size_t)gq * HID + lane * 4) = ov;
    }
}

// ---------------------------------------------------------------------------
// Kernel 4: out = h @ W2 + b2   (32768 x 128, K=256; 256 blocks)
// ---------------------------------------------------------------------------
__global__ __launch_bounds__(256) void gemm2(
    const ushort* __restrict__ h, const ushort* __restrict__ W2T,
    const float* __restrict__ b2, float* __restrict__ out)
{
    __shared__ ushort Ast[128 * 32];
    __shared__ ushort Bst[128 * 32];

    const int tid = threadIdx.x;
    f32x16 acc[2][2];
#pragma unroll
    for (int i = 0; i < 2; ++i)
#pragma unroll
        for (int j = 0; j < 2; ++j)
#pragma unroll
            for (int e = 0; e < 16; ++e) acc[i][j][e] = 0.0f;

    const long rowbase = (long)blockIdx.x * 128;
    gemm_acc128(h, HID, W2T, HID, HID / 32, rowbase, 0, tid, Ast, Bst, acc);

    const int wave = tid >> 6, lane = tid & 63;
    const int wr = wave >> 1, wc = wave & 1;
    const int l31 = lane & 31, kc0 = lane >> 5;
#pragma unroll
    for (int mf = 0; mf < 2; ++mf)
#pragma unroll
        for (int nf = 0; nf < 2; ++nf) {
            const int col = wc * 64 + nf * 32 + l31;
            const float b2v = b2[col];
#pragma unroll
            for (int e = 0; e < 16; ++e) {
                const int rl = wr * 64 + mf * 32 + (e & 3) + ((e >> 2) << 3) + (kc0 << 2);
                out[(rowbase + rl) * COUT + col] = acc[mf][nf][e] + b2v;
            }
        }
}

// ---------------------------------------------------------------------------
extern "C" void kernel_launch(void* const* d_in, const int* in_sizes, int n_in,
                              void* d_out, int out_size, void* d_ws, size_t ws_size,
                              hipStream_t stream)
{
    const float* x        = (const float*)d_in[0];
    const float* pos      = (const float*)d_in[1];
    const float* x_skip   = (const float*)d_in[2];
    const float* pos_skip = (const float*)d_in[3];
    const float* W1       = (const float*)d_in[4];
    const float* b1       = (const float*)d_in[5];
    const float* W2       = (const float*)d_in[6];
    const float* b2       = (const float*)d_in[7];

    float* out = (float*)d_out;

    // workspace: xb 4MB | xsb 8MB | Y 4MB | Z 16MB | h 16MB | W1T | W2T | pos4
    char* wp = (char*)d_ws;
    ushort* xb  = (ushort*)wp; wp += (size_t)Bn * Nn * CIN * 2;      // 4 MB
    ushort* xsb = (ushort*)wp; wp += (size_t)Bn * Mn * CSKIP * 2;    // 8 MB
    ushort* Yb  = (ushort*)wp; wp += (size_t)Bn * Nn * HID * 2;      // 4 MB
    ushort* Zb  = (ushort*)wp; wp += (size_t)Bn * Mn * HID * 2;      // 16 MB
    ushort* hb  = (ushort*)wp; wp += (size_t)Bn * Mn * HID * 2;      // 16 MB
    ushort* W1T = (ushort*)wp; wp += (size_t)HID * KTOT * 2;         // 192 KB
    ushort* W2T = (ushort*)wp; wp += (size_t)COUT * HID * 2;         // 64 KB
    float4* pos4 = (float4*)wp;                                      // 128 KB

    // 1) prep: converts + pos4 + tail
    prep_kernel<<<dim3(6816), 256, 0, stream>>>(
        x, x_skip, pos, pos_skip, W1, W2, xb, xsb, W1T, W2T, pos4,
        out + (size_t)Bn * Mn * COUT);

    // 2) Y = xb @ W1[:256], Z = xsb @ W1[256:]
    yz_gemm<<<dim3(640), 256, 0, stream>>>(xb, xsb, W1T, Yb, Zb);

    // 3) KNN select (R7-exact) + h = relu(sum w*Y + Z + b1)
    knn_h<<<dim3(2048), 256, 0, stream>>>(pos4, pos_skip, Yb, Zb, b1, hb);

    // 4) out = h @ W2 + b2
    gemm2<<<dim3(256), 256, 0, stream>>>(hb, W2T, b2, out);
}